// Round 12
// baseline (736.476 us; speedup 1.0000x reference)
//
#include <hip/hip_runtime.h>
#include <hip/hip_bf16.h>
#include <math.h>

#define NN 512

typedef __attribute__((ext_vector_type(8))) short short8;
typedef __attribute__((ext_vector_type(4))) float f32x4;

__device__ __forceinline__ float selu_f(float x) {
    const float sc = 1.0507009873554805f, al = 1.6732632423543772f;
    return x > 0.f ? sc * x : sc * al * expm1f(x);
}
__device__ __forceinline__ unsigned short f2b(float f) {
    unsigned int u = __float_as_uint(f);
    unsigned int r = (u + 0x7fffu + ((u >> 16) & 1u)) >> 16;
    return (unsigned short)r;
}
__device__ __forceinline__ float b2f(unsigned short h) {
    return __uint_as_float(((unsigned int)h) << 16);
}
__device__ __forceinline__ float ulo(unsigned int u) {
    return __uint_as_float(u << 16);
}
__device__ __forceinline__ float uhi(unsigned int u) {
    return __uint_as_float(u & 0xffff0000u);
}
__device__ __forceinline__ unsigned int pk2(float a, float b) {
    return (unsigned int)f2b(a) | ((unsigned int)f2b(b) << 16);
}
__device__ __forceinline__ unsigned int packval(float f) {
    unsigned short hi = f2b(f);
    unsigned short lo = f2b(f - b2f(hi));
    return (unsigned int)hi | ((unsigned int)lo << 16);
}
__device__ __forceinline__ float unpackval(unsigned int u) {
    return b2f((unsigned short)(u & 0xffffu)) + b2f((unsigned short)(u >> 16));
}
__device__ __forceinline__ void gload16(const void* g, void* l) {
    __builtin_amdgcn_global_load_lds(
        (const __attribute__((address_space(1))) unsigned int*)g,
        (__attribute__((address_space(3))) unsigned int*)l, 16, 0, 0);
}

// ---------------- graph construction (f32) ----------------

__global__ __launch_bounds__(64) void nodevec_kernel(
    const float* __restrict__ emb, const float* __restrict__ lw,
    const float* __restrict__ lb, float* __restrict__ nv) {
    int i = blockIdx.x, j = threadIdx.x;
    __shared__ float e_s[64];
    e_s[j] = emb[i * 64 + j];
    __syncthreads();
    float acc = lb[j];
    for (int k = 0; k < 64; k++) acc += e_s[k] * lw[j * 64 + k];
    nv[i * 64 + j] = tanhf(3.0f * acc);
}

__global__ __launch_bounds__(512) void adjacency_kernel(
    const float* __restrict__ nv1, const float* __restrict__ nv2,
    float* __restrict__ adj) {
    int v = blockIdx.x, w = threadIdx.x;
    __shared__ float a1s[64], a2s[64];
    if (threadIdx.x < 64) {
        a1s[threadIdx.x] = nv1[v * 64 + threadIdx.x];
        a2s[threadIdx.x] = nv2[v * 64 + threadIdx.x];
    }
    __syncthreads();
    float acc = 0.f;
    for (int k = 0; k < 64; k++) {
        acc += a1s[k] * nv2[w * 64 + k];
        acc -= a2s[k] * nv1[w * 64 + k];
    }
    adj[v * NN + w] = selu_f(tanhf(3.0f * acc));
}

__global__ __launch_bounds__(256) void topk_kernel(
    float* __restrict__ adj, float* __restrict__ rowsump) {
    __shared__ float orig[512], srt[512];
    __shared__ unsigned char keep[512];
    __shared__ float red[256];
    int v = blockIdx.x, t = threadIdx.x;
    orig[t] = adj[v * NN + t];
    orig[t + 256] = adj[v * NN + t + 256];
    srt[t] = orig[t];
    srt[t + 256] = orig[t + 256];
    __syncthreads();
    for (int k = 2; k <= 512; k <<= 1) {
        for (int j = k >> 1; j > 0; j >>= 1) {
            for (int pass = 0; pass < 2; ++pass) {
                int i = t + pass * 256;
                int ixj = i ^ j;
                if (ixj > i) {
                    bool up = ((i & k) == 0);
                    float a = srt[i], b = srt[ixj];
                    if ((a > b) == up) { srt[i] = b; srt[ixj] = a; }
                }
            }
            __syncthreads();
        }
    }
    float thr = srt[256];
    if (t == 0) {
        int g = 0;
        for (int i = 0; i < 512; i++) if (srt[i] > thr) g++;
        int quota = 256 - g;
        for (int w = 0; w < 512; w++) {
            float x = orig[w];
            bool kp = false;
            if (x > thr) kp = true;
            else if (x == thr && quota > 0) { kp = true; quota--; }
            keep[w] = kp ? 1 : 0;
        }
    }
    __syncthreads();
    float part = 0.f;
    for (int pass = 0; pass < 2; pass++) {
        int w = t + pass * 256;
        float val = keep[w] ? orig[w] : 0.0f;
        adj[v * NN + w] = val;
        part += val;
    }
    red[t] = part;
    __syncthreads();
    if (t < 128) red[t] += red[t + 128];
    __syncthreads();
    if (t < 64) {
        float x = red[t] + red[t + 64];
        for (int m = 32; m; m >>= 1) x += __shfl_xor(x, m, 64);
        if (t == 0) rowsump[v] = x + 1.0f;
    }
}

__global__ __launch_bounds__(256) void colsum_part(
    const float* __restrict__ adp, float* __restrict__ part) {
    int b = blockIdx.x, w = threadIdx.x;
    float s0 = 0.f, s1 = 0.f;
    for (int r = 0; r < 32; r++) {
        s0 += adp[(b * 32 + r) * 512 + w];
        s1 += adp[(b * 32 + r) * 512 + w + 256];
    }
    part[b * 512 + w] = s0;
    part[b * 512 + w + 256] = s1;
}
__global__ __launch_bounds__(512) void colsum_red(
    const float* __restrict__ part, float* __restrict__ colsum) {
    int w = threadIdx.x;
    float s = 0.f;
    for (int b = 0; b < 16; b++) s += part[b * 512 + w];
    colsum[w] = s;
}

// adjacency stored hi/lo split: aT[w][0..511]=hi, aT[w][512..1023]=lo
__global__ __launch_bounds__(256) void normalize_kernel(
    const float* __restrict__ adp, const float* __restrict__ rowsump,
    const float* __restrict__ colsum, unsigned short* __restrict__ a1T,
    unsigned short* __restrict__ a2T) {
    int w = blockIdx.x;
    for (int v = threadIdx.x; v < NN; v += 256) {
        float d = (v == w) ? 1.0f : 0.0f;
        float f1 = (adp[v * NN + w] + d) / rowsump[v];
        float f2 = (adp[w * NN + v] + d) / (colsum[v] + 1.0f);
        unsigned short h1 = f2b(f1), h2 = f2b(f2);
        a1T[w * 1024 + v] = h1;
        a1T[w * 1024 + 512 + v] = f2b(f1 - b2f(h1));
        a2T[w * 1024 + v] = h2;
        a2T[w * 1024 + 512 + v] = f2b(f2 - b2f(h2));
    }
}

// ---------------- main pipeline ----------------
// h storage: row j = (n*64+l)*32 + c  (c INNERMOST), [j][1024] bf16 hi/lo.

__global__ __launch_bounds__(256) void start_kernel(
    const float* __restrict__ x, const float* __restrict__ sw,
    const float* __restrict__ sb, unsigned int* __restrict__ h_u) {
    int n = blockIdx.x >> 6, l = blockIdx.x & 63;
    int t = threadIdx.x;
    float x0 = x[(n * 512 + 2 * t) * 64 + l];
    float x1 = x[(n * 512 + 2 * t + 1) * 64 + l];
#pragma unroll
    for (int c = 0; c < 32; c++) {
        float wc = sw[c], bc = sb[c];
        float f0 = x0 * wc + bc;
        float f1 = x1 * wc + bc;
        unsigned short h0 = f2b(f0), h1 = f2b(f1);
        float l0 = f0 - b2f(h0), l1 = f1 - b2f(h1);
        int j = (n * 64 + l) * 32 + c;
        h_u[j * 512 + t] = (unsigned int)h0 | ((unsigned int)h1 << 16);
        h_u[j * 512 + 256 + t] = pk2(l0, l1);
    }
}

// Hop-1 paired propagation (shared A); XCD-chunked remap. Rows opaque.
__global__ __launch_bounds__(256, 2) void prop_hop1(
    const unsigned short* __restrict__ HA, const unsigned short* __restrict__ base,
    const unsigned short* __restrict__ AT1,
    const unsigned short* __restrict__ AT2,
    unsigned short* __restrict__ dst1, unsigned short* __restrict__ dst2) {
    __shared__ __align__(16) short At1[128 * 64];
    __shared__ __align__(16) short Bt1[64 * 64];
    __shared__ __align__(16) short Bt2[64 * 64];
    int t = threadIdx.x;
    int lane = t & 63;
    int wid = t >> 6;
    int wm = wid >> 1, wn = wid & 1;
    int flat = blockIdx.y * 64 + blockIdx.x;
    int wid_ = (flat & 7) * 64 + (flat >> 3);
    int local = wid_ & 63;
    int j0 = (((wid_ >> 6) << 3) + (local & 7)) << 7;
    int w0 = (local >> 3) << 6;
    f32x4 acc1[4][2], acc2[4][2];
#pragma unroll
    for (int m = 0; m < 4; m++)
#pragma unroll
        for (int n = 0; n < 2; n++) {
            acc1[m][n] = (f32x4)0.f;
            acc2[m][n] = (f32x4)0.f;
        }
    int l15 = lane & 15;
    int lhi = lane >> 4;
    int rsw = l15 & 7;
    for (int tk = 0; tk < 24; tk++) {
        int kk = tk << 6;
        int ca = (kk < 1024) ? kk : (kk - 1024);
        int cb = (kk < 512) ? kk : (kk - 512);
#pragma unroll
        for (int it = 0; it < 4; it++) {
            int slot = it * 256 + t;
            int r = slot >> 3, sl = slot & 7;
            int src = (sl ^ (r & 7)) << 3;
            gload16(HA + (j0 + r) * 1024 + ca + src, &At1[slot * 8]);
        }
#pragma unroll
        for (int it = 0; it < 2; it++) {
            int slot = it * 256 + t;
            int r = slot >> 3, sl = slot & 7;
            int src = (sl ^ (r & 7)) << 3;
            gload16(AT1 + (w0 + r) * 1024 + cb + src, &Bt1[slot * 8]);
            gload16(AT2 + (w0 + r) * 1024 + cb + src, &Bt2[slot * 8]);
        }
        __syncthreads();
#pragma unroll
        for (int kh = 0; kh < 2; kh++) {
            int soff = ((kh * 4 + lhi) ^ rsw) << 3;
            short8 a1[4], b1[2], b2[2];
#pragma unroll
            for (int m = 0; m < 4; m++)
                a1[m] =
                    *(const short8*)&At1[(wm * 64 + m * 16 + l15) * 64 + soff];
#pragma unroll
            for (int n = 0; n < 2; n++) {
                b1[n] =
                    *(const short8*)&Bt1[(wn * 32 + n * 16 + l15) * 64 + soff];
                b2[n] =
                    *(const short8*)&Bt2[(wn * 32 + n * 16 + l15) * 64 + soff];
            }
#pragma unroll
            for (int m = 0; m < 4; m++)
#pragma unroll
                for (int n = 0; n < 2; n++) {
                    acc1[m][n] = __builtin_amdgcn_mfma_f32_16x16x32_bf16(
                        a1[m], b1[n], acc1[m][n], 0, 0, 0);
                    acc2[m][n] = __builtin_amdgcn_mfma_f32_16x16x32_bf16(
                        a1[m], b2[n], acc2[m][n], 0, 0, 0);
                }
        }
        __syncthreads();
    }
#pragma unroll
    for (int m = 0; m < 4; m++) {
#pragma unroll
        for (int n = 0; n < 2; n++) {
#pragma unroll
            for (int r = 0; r < 4; r++) {
                int row = j0 + wm * 64 + m * 16 + lhi * 4 + r;
                int col = w0 + wn * 32 + n * 16 + l15;
                int ih = row * 1024 + col;
                float bf = b2f(base[ih]) + b2f(base[ih + 512]);
                float f1 = 0.05f * bf + 0.95f * acc1[m][n][r];
                float f2 = 0.05f * bf + 0.95f * acc2[m][n][r];
                unsigned short h1 = f2b(f1);
                unsigned short h2 = f2b(f2);
                dst1[ih] = h1;
                dst1[ih + 512] = f2b(f1 - b2f(h1));
                dst2[ih] = h2;
                dst2[ih + 512] = f2b(f2 - b2f(h2));
            }
        }
    }
}

// Hop-2 + fused channel-mix. Rows j=(n,l,c): block's 128 rows = 4 complete
// (n,l) groups x 32 c -> the c-contraction closes in-block. s3/s4 never
// touch global; weights via scalar path. Output nxt written directly.
__global__ __launch_bounds__(256, 2) void prop2mix(
    const unsigned short* __restrict__ HA, const unsigned short* __restrict__ HB,
    const unsigned short* __restrict__ base,
    const unsigned short* __restrict__ AT1,
    const unsigned short* __restrict__ AT2,
    const float* __restrict__ w1, const float* __restrict__ b1,
    const float* __restrict__ w2, const float* __restrict__ b2,
    unsigned short* __restrict__ nxt) {
    __shared__ __align__(16) char smem[65536];
    short* At1 = (short*)smem;                 // 16 KB
    short* At2 = (short*)(smem + 16384);       // 16 KB
    short* Bt1 = (short*)(smem + 32768);       // 8 KB
    short* Bt2 = (short*)(smem + 40960);       // 8 KB
    unsigned int* S3 = (unsigned int*)smem;            // 32 KB (aliases tiles)
    unsigned int* S4 = (unsigned int*)(smem + 32768);  // 32 KB

    int t = threadIdx.x;
    int lane = t & 63;
    int wid = t >> 6;
    int wm = wid >> 1, wn = wid & 1;
    int flat = blockIdx.y * 64 + blockIdx.x;
    int wid_ = (flat & 7) * 64 + (flat >> 3);
    int local = wid_ & 63;
    int j0 = (((wid_ >> 6) << 3) + (local & 7)) << 7;
    int w0 = (local >> 3) << 6;
    f32x4 acc1[4][2], acc2[4][2];
#pragma unroll
    for (int m = 0; m < 4; m++)
#pragma unroll
        for (int n = 0; n < 2; n++) {
            acc1[m][n] = (f32x4)0.f;
            acc2[m][n] = (f32x4)0.f;
        }
    int l15 = lane & 15;
    int lhi = lane >> 4;
    int rsw = l15 & 7;
    for (int tk = 0; tk < 24; tk++) {
        int kk = tk << 6;
        int ca = (kk < 1024) ? kk : (kk - 1024);
        int cb = (kk < 512) ? kk : (kk - 512);
#pragma unroll
        for (int it = 0; it < 4; it++) {
            int slot = it * 256 + t;
            int r = slot >> 3, sl = slot & 7;
            int src = (sl ^ (r & 7)) << 3;
            gload16(HA + (j0 + r) * 1024 + ca + src, &At1[slot * 8]);
            gload16(HB + (j0 + r) * 1024 + ca + src, &At2[slot * 8]);
        }
#pragma unroll
        for (int it = 0; it < 2; it++) {
            int slot = it * 256 + t;
            int r = slot >> 3, sl = slot & 7;
            int src = (sl ^ (r & 7)) << 3;
            gload16(AT1 + (w0 + r) * 1024 + cb + src, &Bt1[slot * 8]);
            gload16(AT2 + (w0 + r) * 1024 + cb + src, &Bt2[slot * 8]);
        }
        __syncthreads();
#pragma unroll
        for (int kh = 0; kh < 2; kh++) {
            int soff = ((kh * 4 + lhi) ^ rsw) << 3;
            short8 a1[4], a2[4], b1v[2], b2v[2];
#pragma unroll
            for (int m = 0; m < 4; m++) {
                a1[m] =
                    *(const short8*)&At1[(wm * 64 + m * 16 + l15) * 64 + soff];
                a2[m] =
                    *(const short8*)&At2[(wm * 64 + m * 16 + l15) * 64 + soff];
            }
#pragma unroll
            for (int n = 0; n < 2; n++) {
                b1v[n] =
                    *(const short8*)&Bt1[(wn * 32 + n * 16 + l15) * 64 + soff];
                b2v[n] =
                    *(const short8*)&Bt2[(wn * 32 + n * 16 + l15) * 64 + soff];
            }
#pragma unroll
            for (int m = 0; m < 4; m++)
#pragma unroll
                for (int n = 0; n < 2; n++) {
                    acc1[m][n] = __builtin_amdgcn_mfma_f32_16x16x32_bf16(
                        a1[m], b1v[n], acc1[m][n], 0, 0, 0);
                    acc2[m][n] = __builtin_amdgcn_mfma_f32_16x16x32_bf16(
                        a2[m], b2v[n], acc2[m][n], 0, 0, 0);
                }
        }
        __syncthreads();
    }
    // phase 1: blend with base, pack s3/s4 into LDS (tiles are dead).
#pragma unroll
    for (int m = 0; m < 4; m++) {
#pragma unroll
        for (int n = 0; n < 2; n++) {
#pragma unroll
            for (int r = 0; r < 4; r++) {
                int rl = wm * 64 + m * 16 + lhi * 4 + r;
                int cl = wn * 32 + n * 16 + l15;
                int ih = (j0 + rl) * 1024 + (w0 + cl);
                float bf = b2f(base[ih]) + b2f(base[ih + 512]);
                S3[rl * 64 + cl] = packval(0.05f * bf + 0.95f * acc1[m][n][r]);
                S4[rl * 64 + cl] = packval(0.05f * bf + 0.95f * acc2[m][n][r]);
            }
        }
    }
    __syncthreads();
    // phase 2: channel mix. wave g owns (n,l) group g; lane = v col.
    {
        int g = t >> 6, vl = t & 63;
        int jg = j0 + g * 32;  // = (n*64+l)*32
        float acc_o[32];
#pragma unroll
        for (int o = 0; o < 32; o++) acc_o[o] = b1[o] + b2[o];
#pragma unroll 1
        for (int cc = 0; cc < 4; cc++) {
            float x0[8], xa[8], xb[8], xc[8], xd[8];
#pragma unroll
            for (int c8 = 0; c8 < 8; c8++) {
                int c = cc * 8 + c8;
                int ih = (jg + c) * 1024 + w0 + vl;
                x0[c8] = b2f(base[ih]) + b2f(base[ih + 512]);
                xa[c8] = b2f(HA[ih]) + b2f(HA[ih + 512]);
                xc[c8] = b2f(HB[ih]) + b2f(HB[ih + 512]);
                xb[c8] = unpackval(S3[(g * 32 + c) * 64 + vl]);
                xd[c8] = unpackval(S4[(g * 32 + c) * 64 + vl]);
            }
#pragma unroll
            for (int o = 0; o < 32; o++) {
#pragma unroll
                for (int c8 = 0; c8 < 8; c8++) {
                    int c = cc * 8 + c8;
                    acc_o[o] += x0[c8] * w1[o * 96 + c] +
                                x0[c8] * w2[o * 96 + c] +
                                xa[c8] * w1[o * 96 + 32 + c] +
                                xb[c8] * w1[o * 96 + 64 + c] +
                                xc[c8] * w2[o * 96 + 32 + c] +
                                xd[c8] * w2[o * 96 + 64 + c];
                }
            }
        }
#pragma unroll
        for (int o = 0; o < 32; o++) {
            int ih = (jg + o) * 1024 + w0 + vl;
            float f = acc_o[o];
            unsigned short hi = f2b(f);
            nxt[ih] = hi;
            nxt[ih + 512] = f2b(f - b2f(hi));
        }
    }
}

// LayerNorm over l, in place; rows (n*64+l)*C + cg. grid = 4*C.
__global__ __launch_bounds__(256) void ln_kernel(
    unsigned int* __restrict__ h_u, const float* __restrict__ lw,
    const float* __restrict__ lb, int C) {
    int b = blockIdx.x;
    int n = b / C, cg = b % C;
    int t = threadIdx.x;
    float s0 = 0.f, s1 = 0.f, q0 = 0.f, q1 = 0.f;
    for (int l = 0; l < 64; l++) {
        unsigned int base = (unsigned int)(((n * 64 + l) * C + cg) * 512 + t);
        unsigned int hi = h_u[base];
        unsigned int lo = h_u[base + 256];
        float f0 = ulo(hi) + ulo(lo), f1 = uhi(hi) + uhi(lo);
        s0 += f0; s1 += f1;
        q0 += f0 * f0; q1 += f1 * f1;
    }
    float m0 = s0 * (1.f / 64.f), m1 = s1 * (1.f / 64.f);
    float v0 = fmaxf(q0 * (1.f / 64.f) - m0 * m0, 0.f);
    float v1 = fmaxf(q1 * (1.f / 64.f) - m1 * m1, 0.f);
    float i0 = 1.f / sqrtf(v0 + 1e-12f);
    float i1 = 1.f / sqrtf(v1 + 1e-12f);
    for (int l = 0; l < 64; l++) {
        unsigned int base = (unsigned int)(((n * 64 + l) * C + cg) * 512 + t);
        unsigned int hi = h_u[base];
        unsigned int lo = h_u[base + 256];
        float wl = lw[l], bl = lb[l];
        float f0 = wl * (ulo(hi) + ulo(lo) - m0) * i0 + bl;
        float f1 = wl * (uhi(hi) + uhi(lo) - m1) * i1 + bl;
        unsigned short p0 = f2b(f0), p1 = f2b(f1);
        h_u[base] = (unsigned int)p0 | ((unsigned int)p1 << 16);
        h_u[base + 256] = pk2(f0 - b2f(p0), f1 - b2f(p1));
    }
}

// e1[(n,l,o1)][v] = selu(b1 + sum_c W1[o1,c]*h[(n,l,c)][v]); e1 single bf16.
__global__ __launch_bounds__(256) void endmix1(
    const unsigned int* __restrict__ h, const float* __restrict__ w1,
    const float* __restrict__ b1, unsigned int* __restrict__ e1u) {
    __shared__ float wsT[32 * 64];
    int bid = blockIdx.x;
    int vc = bid & 3, l = (bid >> 2) & 63, n = bid >> 8;
    int t = threadIdx.x;
    int vl = t & 63, q = t >> 6;
    for (int i = t; i < 2048; i += 256) {
        int o1 = i >> 5, c = i & 31;
        wsT[c * 64 + o1] = w1[i];
    }
    __syncthreads();
    float acc[16][2];
#pragma unroll
    for (int oo = 0; oo < 16; oo++) {
        float bb = b1[q * 16 + oo];
        acc[oo][0] = bb;
        acc[oo][1] = bb;
    }
    int uoff = vc * 64 + vl;
    int nlb = (n * 64 + l) * 32;
    for (int c = 0; c < 32; c++) {
        int j = nlb + c;
        unsigned int uh = h[j * 512 + uoff], ul = h[j * 512 + 256 + uoff];
        float xl = ulo(uh) + ulo(ul), xh = uhi(uh) + uhi(ul);
#pragma unroll
        for (int ov = 0; ov < 4; ov++) {
            float4 wv = *(const float4*)&wsT[c * 64 + q * 16 + ov * 4];
            acc[ov * 4 + 0][0] += xl * wv.x;
            acc[ov * 4 + 0][1] += xh * wv.x;
            acc[ov * 4 + 1][0] += xl * wv.y;
            acc[ov * 4 + 1][1] += xh * wv.y;
            acc[ov * 4 + 2][0] += xl * wv.z;
            acc[ov * 4 + 2][1] += xh * wv.z;
            acc[ov * 4 + 3][0] += xl * wv.w;
            acc[ov * 4 + 3][1] += xh * wv.w;
        }
    }
    int nlb2 = (n * 64 + l) * 64;
#pragma unroll
    for (int oo = 0; oo < 16; oo++) {
        int j2 = nlb2 + q * 16 + oo;
        e1u[j2 * 256 + uoff] = pk2(selu_f(acc[oo][0]), selu_f(acc[oo][1]));
    }
}

// e2[(n,l,o2)][v] = b2 + sum_o1 W2[o2,o1]*e1; hi/lo output.
__global__ __launch_bounds__(256) void endmix2(
    const unsigned int* __restrict__ e1u, const float* __restrict__ w2,
    const float* __restrict__ b2, unsigned int* __restrict__ e2u) {
    __shared__ float wsT[64 * 64];
    int bid = blockIdx.x;
    int vc = bid & 3, l = (bid >> 2) & 63, n = bid >> 8;
    int t = threadIdx.x;
    int vl = t & 63, q = t >> 6;
    for (int i = t; i < 4096; i += 256) {
        int o2 = i >> 6, o1 = i & 63;
        wsT[o1 * 64 + o2] = w2[i];
    }
    __syncthreads();
    float acc[16][2];
#pragma unroll
    for (int oo = 0; oo < 16; oo++) {
        float bb = b2[q * 16 + oo];
        acc[oo][0] = bb;
        acc[oo][1] = bb;
    }
    int uoff = vc * 64 + vl;
    int nlb = (n * 64 + l) * 64;
    for (int o1 = 0; o1 < 64; o1++) {
        unsigned int u = e1u[(nlb + o1) * 256 + uoff];
        float xl = ulo(u), xh = uhi(u);
#pragma unroll
        for (int ov = 0; ov < 4; ov++) {
            float4 wv = *(const float4*)&wsT[o1 * 64 + q * 16 + ov * 4];
            acc[ov * 4 + 0][0] += xl * wv.x;
            acc[ov * 4 + 0][1] += xh * wv.x;
            acc[ov * 4 + 1][0] += xl * wv.y;
            acc[ov * 4 + 1][1] += xh * wv.y;
            acc[ov * 4 + 2][0] += xl * wv.z;
            acc[ov * 4 + 2][1] += xh * wv.z;
            acc[ov * 4 + 3][0] += xl * wv.w;
            acc[ov * 4 + 3][1] += xh * wv.w;
        }
    }
#pragma unroll
    for (int oo = 0; oo < 16; oo++) {
        int j3 = nlb + q * 16 + oo;
        float a0 = acc[oo][0], a1 = acc[oo][1];
        unsigned short hi0 = f2b(a0), hi1 = f2b(a1);
        e2u[j3 * 512 + uoff] = (unsigned int)hi0 | ((unsigned int)hi1 << 16);
        e2u[j3 * 512 + 256 + uoff] = pk2(a0 - b2f(hi0), a1 - b2f(hi1));
    }
}

// out[n][l][v] = sum_o2 e2[(n,l,o2)][v]. grid 256 = n*64+l.
__global__ __launch_bounds__(256) void sum_o2(
    const unsigned int* __restrict__ e2u, float* __restrict__ out) {
    int nl = blockIdx.x;
    int t = threadIdx.x;
    float s0 = 0.f, s1 = 0.f;
    for (int o2 = 0; o2 < 64; o2++) {
        int j3 = nl * 64 + o2;
        unsigned int hi = e2u[j3 * 512 + t];
        unsigned int lo = e2u[j3 * 512 + 256 + t];
        s0 += ulo(hi) + ulo(lo);
        s1 += uhi(hi) + uhi(lo);
    }
    float2 r;
    r.x = s0;
    r.y = s1;
    *(float2*)&out[(size_t)nl * 512 + 2 * t] = r;
}

// ---------------- launch ----------------

extern "C" void kernel_launch(void* const* d_in, const int* in_sizes, int n_in,
                              void* d_out, int out_size, void* d_ws,
                              size_t ws_size, hipStream_t stream) {
    const float* x = (const float*)d_in[0];
    const float* emb1 = (const float*)d_in[1];
    const float* emb2 = (const float*)d_in[2];
    const float* lin1_w = (const float*)d_in[3];
    const float* lin1_b = (const float*)d_in[4];
    const float* lin2_w = (const float*)d_in[5];
    const float* lin2_b = (const float*)d_in[6];
    const float* start_w = (const float*)d_in[7];
    const float* start_b = (const float*)d_in[8];
    const float* g1_w = (const float*)d_in[9];
    const float* g1_b = (const float*)d_in[10];
    const float* g2_w = (const float*)d_in[11];
    const float* g2_b = (const float*)d_in[12];
    const float* ln_w = (const float*)d_in[13];
    const float* ln_b = (const float*)d_in[14];
    const float* end1_w = (const float*)d_in[15];
    const float* end1_b = (const float*)d_in[16];
    const float* end2_w = (const float*)d_in[17];
    const float* end2_b = (const float*)d_in[18];
    float* out = (float*)d_out;

    char* ws = (char*)d_ws;
    float* nv1 = (float*)(ws + 0);
    float* nv2 = (float*)(ws + 131072);
    float* adp = (float*)(ws + 262144);
    unsigned short* a1T = (unsigned short*)(ws + 1310720);
    unsigned short* a2T = (unsigned short*)(ws + 2359296);
    float* rowsump = (float*)(ws + 3407872);
    float* colsum = (float*)(ws + 3409920);
    float* cspart = (float*)(ws + 3412992);
    unsigned short* hA = (unsigned short*)(ws + 4194304);   // 16 MB
    unsigned short* hB = (unsigned short*)(ws + 20971520);  // 16 MB
    unsigned short* s1 = (unsigned short*)(ws + 37748736);  // 16 MB
    unsigned short* s2 = (unsigned short*)(ws + 54525952);  // 16 MB
    unsigned short* e1 = (unsigned short*)(ws + 71303168);  // 8 MB
    unsigned short* e2 = (unsigned short*)(ws + 88080384);  // 16 MB

    nodevec_kernel<<<512, 64, 0, stream>>>(emb1, lin1_w, lin1_b, nv1);
    nodevec_kernel<<<512, 64, 0, stream>>>(emb2, lin2_w, lin2_b, nv2);
    adjacency_kernel<<<512, 512, 0, stream>>>(nv1, nv2, adp);
    topk_kernel<<<512, 256, 0, stream>>>(adp, rowsump);
    colsum_part<<<16, 256, 0, stream>>>(adp, cspart);
    colsum_red<<<1, 512, 0, stream>>>(cspart, colsum);
    normalize_kernel<<<512, 256, 0, stream>>>(adp, rowsump, colsum, a1T, a2T);

    start_kernel<<<256, 256, 0, stream>>>(x, start_w, start_b, (unsigned int*)hA);

    dim3 pgrid(64, 8);
    unsigned short* cur = hA;
    unsigned short* nxt = hB;
    for (int layer = 0; layer < 2; layer++) {
        const float* w1 = g1_w + layer * 32 * 96;
        const float* bb1 = g1_b + layer * 32;
        const float* w2 = g2_w + layer * 32 * 96;
        const float* bb2 = g2_b + layer * 32;
        prop_hop1<<<pgrid, 256, 0, stream>>>(cur, cur, a1T, a2T, s1, s2);
        prop2mix<<<pgrid, 256, 0, stream>>>(s1, s2, cur, a1T, a2T, w1, bb1,
                                            w2, bb2, nxt);
        unsigned short* tmp = cur;
        cur = nxt;
        nxt = tmp;
    }

    // end stage: LN#1 -> end1+selu -> end2 -> LN#2 -> sum over o2
    ln_kernel<<<128, 256, 0, stream>>>((unsigned int*)cur, ln_w, ln_b, 32);
    endmix1<<<1024, 256, 0, stream>>>((const unsigned int*)cur, end1_w, end1_b,
                                      (unsigned int*)e1);
    endmix2<<<1024, 256, 0, stream>>>((const unsigned int*)e1, end2_w, end2_b,
                                      (unsigned int*)e2);
    ln_kernel<<<256, 256, 0, stream>>>((unsigned int*)e2, ln_w, ln_b, 64);
    sum_o2<<<256, 256, 0, stream>>>((const unsigned int*)e2, out);
}

// Round 13
// 416.492 us; speedup vs baseline: 1.7683x; 1.7683x over previous
//
#include <hip/hip_runtime.h>
#include <hip/hip_bf16.h>
#include <math.h>

#define NN 512

typedef __attribute__((ext_vector_type(8))) short short8;
typedef __attribute__((ext_vector_type(4))) float f32x4;

__device__ __forceinline__ float selu_f(float x) {
    const float sc = 1.0507009873554805f, al = 1.6732632423543772f;
    return x > 0.f ? sc * x : sc * al * expm1f(x);
}
__device__ __forceinline__ unsigned short f2b(float f) {
    unsigned int u = __float_as_uint(f);
    unsigned int r = (u + 0x7fffu + ((u >> 16) & 1u)) >> 16;
    return (unsigned short)r;
}
__device__ __forceinline__ float b2f(unsigned short h) {
    return __uint_as_float(((unsigned int)h) << 16);
}
__device__ __forceinline__ float ulo(unsigned int u) {
    return __uint_as_float(u << 16);
}
__device__ __forceinline__ float uhi(unsigned int u) {
    return __uint_as_float(u & 0xffff0000u);
}
__device__ __forceinline__ unsigned int pk2(float a, float b) {
    return (unsigned int)f2b(a) | ((unsigned int)f2b(b) << 16);
}
__device__ __forceinline__ void gload16(const void* g, void* l) {
    __builtin_amdgcn_global_load_lds(
        (const __attribute__((address_space(1))) unsigned int*)g,
        (__attribute__((address_space(3))) unsigned int*)l, 16, 0, 0);
}

// ---------------- graph construction (f32) ----------------

__global__ __launch_bounds__(64) void nodevec_kernel(
    const float* __restrict__ emb, const float* __restrict__ lw,
    const float* __restrict__ lb, float* __restrict__ nv) {
    int i = blockIdx.x, j = threadIdx.x;
    __shared__ float e_s[64];
    e_s[j] = emb[i * 64 + j];
    __syncthreads();
    float acc = lb[j];
    for (int k = 0; k < 64; k++) acc += e_s[k] * lw[j * 64 + k];
    nv[i * 64 + j] = tanhf(3.0f * acc);
}

__global__ __launch_bounds__(512) void adjacency_kernel(
    const float* __restrict__ nv1, const float* __restrict__ nv2,
    float* __restrict__ adj) {
    int v = blockIdx.x, w = threadIdx.x;
    __shared__ float a1s[64], a2s[64];
    if (threadIdx.x < 64) {
        a1s[threadIdx.x] = nv1[v * 64 + threadIdx.x];
        a2s[threadIdx.x] = nv2[v * 64 + threadIdx.x];
    }
    __syncthreads();
    float acc = 0.f;
    for (int k = 0; k < 64; k++) {
        acc += a1s[k] * nv2[w * 64 + k];
        acc -= a2s[k] * nv1[w * 64 + k];
    }
    adj[v * NN + w] = selu_f(tanhf(3.0f * acc));
}

__global__ __launch_bounds__(256) void topk_kernel(
    float* __restrict__ adj, float* __restrict__ rowsump) {
    __shared__ float orig[512], srt[512];
    __shared__ unsigned char keep[512];
    __shared__ float red[256];
    int v = blockIdx.x, t = threadIdx.x;
    orig[t] = adj[v * NN + t];
    orig[t + 256] = adj[v * NN + t + 256];
    srt[t] = orig[t];
    srt[t + 256] = orig[t + 256];
    __syncthreads();
    for (int k = 2; k <= 512; k <<= 1) {
        for (int j = k >> 1; j > 0; j >>= 1) {
            for (int pass = 0; pass < 2; ++pass) {
                int i = t + pass * 256;
                int ixj = i ^ j;
                if (ixj > i) {
                    bool up = ((i & k) == 0);
                    float a = srt[i], b = srt[ixj];
                    if ((a > b) == up) { srt[i] = b; srt[ixj] = a; }
                }
            }
            __syncthreads();
        }
    }
    float thr = srt[256];
    if (t == 0) {
        int g = 0;
        for (int i = 0; i < 512; i++) if (srt[i] > thr) g++;
        int quota = 256 - g;
        for (int w = 0; w < 512; w++) {
            float x = orig[w];
            bool kp = false;
            if (x > thr) kp = true;
            else if (x == thr && quota > 0) { kp = true; quota--; }
            keep[w] = kp ? 1 : 0;
        }
    }
    __syncthreads();
    float part = 0.f;
    for (int pass = 0; pass < 2; pass++) {
        int w = t + pass * 256;
        float val = keep[w] ? orig[w] : 0.0f;
        adj[v * NN + w] = val;
        part += val;
    }
    red[t] = part;
    __syncthreads();
    if (t < 128) red[t] += red[t + 128];
    __syncthreads();
    if (t < 64) {
        float x = red[t] + red[t + 64];
        for (int m = 32; m; m >>= 1) x += __shfl_xor(x, m, 64);
        if (t == 0) rowsump[v] = x + 1.0f;
    }
}

__global__ __launch_bounds__(256) void colsum_part(
    const float* __restrict__ adp, float* __restrict__ part) {
    int b = blockIdx.x, w = threadIdx.x;
    float s0 = 0.f, s1 = 0.f;
    for (int r = 0; r < 32; r++) {
        s0 += adp[(b * 32 + r) * 512 + w];
        s1 += adp[(b * 32 + r) * 512 + w + 256];
    }
    part[b * 512 + w] = s0;
    part[b * 512 + w + 256] = s1;
}
__global__ __launch_bounds__(512) void colsum_red(
    const float* __restrict__ part, float* __restrict__ colsum) {
    int w = threadIdx.x;
    float s = 0.f;
    for (int b = 0; b < 16; b++) s += part[b * 512 + w];
    colsum[w] = s;
}

// adjacency stored hi/lo split: aT[w][0..511]=hi, aT[w][512..1023]=lo
__global__ __launch_bounds__(256) void normalize_kernel(
    const float* __restrict__ adp, const float* __restrict__ rowsump,
    const float* __restrict__ colsum, unsigned short* __restrict__ a1T,
    unsigned short* __restrict__ a2T) {
    int w = blockIdx.x;
    for (int v = threadIdx.x; v < NN; v += 256) {
        float d = (v == w) ? 1.0f : 0.0f;
        float f1 = (adp[v * NN + w] + d) / rowsump[v];
        float f2 = (adp[w * NN + v] + d) / (colsum[v] + 1.0f);
        unsigned short h1 = f2b(f1), h2 = f2b(f2);
        a1T[w * 1024 + v] = h1;
        a1T[w * 1024 + 512 + v] = f2b(f1 - b2f(h1));
        a2T[w * 1024 + v] = h2;
        a2T[w * 1024 + 512 + v] = f2b(f2 - b2f(h2));
    }
}

// ---------------- main pipeline ----------------
// h storage: [j=(n,c,l)][1024] bf16; cols 0..511 = hi, 512..1023 = lo.

__global__ __launch_bounds__(256) void start_kernel(
    const float* __restrict__ x, const float* __restrict__ sw,
    const float* __restrict__ sb, unsigned int* __restrict__ h_u) {
    int n = blockIdx.x >> 6, l = blockIdx.x & 63;
    int t = threadIdx.x;
    float x0 = x[(n * 512 + 2 * t) * 64 + l];
    float x1 = x[(n * 512 + 2 * t + 1) * 64 + l];
#pragma unroll
    for (int c = 0; c < 32; c++) {
        float wc = sw[c], bc = sb[c];
        float f0 = x0 * wc + bc;
        float f1 = x1 * wc + bc;
        unsigned short h0 = f2b(f0), h1 = f2b(f1);
        float l0 = f0 - b2f(h0), l1 = f1 - b2f(h1);
        int j = (n * 32 + c) * 64 + l;
        h_u[j * 512 + t] = (unsigned int)h0 | ((unsigned int)h1 << 16);
        h_u[j * 512 + 256 + t] = pk2(l0, l1);
    }
}

// Paired propagation; XCD-chunked block remap (T1). Round-9 exact (passing).
template <bool SHAREA>
__global__ __launch_bounds__(256, 2) void prop_pair(
    const unsigned short* __restrict__ HA, const unsigned short* __restrict__ HB,
    const unsigned short* __restrict__ base,
    const unsigned short* __restrict__ AT1,
    const unsigned short* __restrict__ AT2,
    unsigned short* __restrict__ dst1, unsigned short* __restrict__ dst2) {
    __shared__ __align__(16) short At1[128 * 64];
    __shared__ __align__(16) short At2[SHAREA ? 8 : 128 * 64];
    __shared__ __align__(16) short Bt1[64 * 64];
    __shared__ __align__(16) short Bt2[64 * 64];
    int t = threadIdx.x;
    int lane = t & 63;
    int wid = t >> 6;
    int wm = wid >> 1, wn = wid & 1;
    int flat = blockIdx.y * 64 + blockIdx.x;
    int wid_ = (flat & 7) * 64 + (flat >> 3);
    int local = wid_ & 63;
    int j0 = (((wid_ >> 6) << 3) + (local & 7)) << 7;
    int w0 = (local >> 3) << 6;
    f32x4 acc1[4][2], acc2[4][2];
#pragma unroll
    for (int m = 0; m < 4; m++)
#pragma unroll
        for (int n = 0; n < 2; n++) {
            acc1[m][n] = (f32x4)0.f;
            acc2[m][n] = (f32x4)0.f;
        }
    int l15 = lane & 15;
    int lhi = lane >> 4;
    int rsw = l15 & 7;
    for (int tk = 0; tk < 24; tk++) {
        int kk = tk << 6;
        int ca = (kk < 1024) ? kk : (kk - 1024);
        int cb = (kk < 512) ? kk : (kk - 512);
#pragma unroll
        for (int it = 0; it < 4; it++) {
            int slot = it * 256 + t;
            int r = slot >> 3, sl = slot & 7;
            int src = (sl ^ (r & 7)) << 3;
            gload16(HA + (j0 + r) * 1024 + ca + src, &At1[slot * 8]);
            if constexpr (!SHAREA)
                gload16(HB + (j0 + r) * 1024 + ca + src, &At2[slot * 8]);
        }
#pragma unroll
        for (int it = 0; it < 2; it++) {
            int slot = it * 256 + t;
            int r = slot >> 3, sl = slot & 7;
            int src = (sl ^ (r & 7)) << 3;
            gload16(AT1 + (w0 + r) * 1024 + cb + src, &Bt1[slot * 8]);
            gload16(AT2 + (w0 + r) * 1024 + cb + src, &Bt2[slot * 8]);
        }
        __syncthreads();
#pragma unroll
        for (int kh = 0; kh < 2; kh++) {
            int soff = ((kh * 4 + lhi) ^ rsw) << 3;
            short8 a1[4], b1[2], b2[2];
#pragma unroll
            for (int m = 0; m < 4; m++)
                a1[m] =
                    *(const short8*)&At1[(wm * 64 + m * 16 + l15) * 64 + soff];
#pragma unroll
            for (int n = 0; n < 2; n++) {
                b1[n] =
                    *(const short8*)&Bt1[(wn * 32 + n * 16 + l15) * 64 + soff];
                b2[n] =
                    *(const short8*)&Bt2[(wn * 32 + n * 16 + l15) * 64 + soff];
            }
            if constexpr (SHAREA) {
#pragma unroll
                for (int m = 0; m < 4; m++)
#pragma unroll
                    for (int n = 0; n < 2; n++) {
                        acc1[m][n] = __builtin_amdgcn_mfma_f32_16x16x32_bf16(
                            a1[m], b1[n], acc1[m][n], 0, 0, 0);
                        acc2[m][n] = __builtin_amdgcn_mfma_f32_16x16x32_bf16(
                            a1[m], b2[n], acc2[m][n], 0, 0, 0);
                    }
            } else {
                short8 a2[4];
#pragma unroll
                for (int m = 0; m < 4; m++)
                    a2[m] = *(const short8*)&At2[(wm * 64 + m * 16 + l15) * 64 +
                                                 soff];
#pragma unroll
                for (int m = 0; m < 4; m++)
#pragma unroll
                    for (int n = 0; n < 2; n++) {
                        acc1[m][n] = __builtin_amdgcn_mfma_f32_16x16x32_bf16(
                            a1[m], b1[n], acc1[m][n], 0, 0, 0);
                        acc2[m][n] = __builtin_amdgcn_mfma_f32_16x16x32_bf16(
                            a2[m], b2[n], acc2[m][n], 0, 0, 0);
                    }
            }
        }
        __syncthreads();
    }
#pragma unroll
    for (int m = 0; m < 4; m++) {
#pragma unroll
        for (int n = 0; n < 2; n++) {
#pragma unroll
            for (int r = 0; r < 4; r++) {
                int row = j0 + wm * 64 + m * 16 + lhi * 4 + r;
                int col = w0 + wn * 32 + n * 16 + l15;
                int ih = row * 1024 + col;
                float bf = b2f(base[ih]) + b2f(base[ih + 512]);
                float f1 = 0.05f * bf + 0.95f * acc1[m][n][r];
                float f2 = 0.05f * bf + 0.95f * acc2[m][n][r];
                unsigned short h1 = f2b(f1);
                unsigned short h2 = f2b(f2);
                dst1[ih] = h1;
                dst1[ih + 512] = f2b(f1 - b2f(h1));
                dst2[ih] = h2;
                dst2[ih + 512] = f2b(f2 - b2f(h2));
            }
        }
    }
}

// chanmix v2: transposed-weight float4 LDS reads + 4 v per thread.
// dst = mix(w1; h0,p1a,p2a) + mix(w2; h0,p1b,p2b), f32-summed, hi/lo out.
__global__ __launch_bounds__(256) void chanmix_v2(
    const unsigned int* __restrict__ h0, const unsigned int* __restrict__ p1a,
    const unsigned int* __restrict__ p2a, const unsigned int* __restrict__ p1b,
    const unsigned int* __restrict__ p2b, const float* __restrict__ w1,
    const float* __restrict__ b1, const float* __restrict__ w2,
    const float* __restrict__ b2, unsigned int* __restrict__ dst_u) {
    __shared__ float wT1[96 * 32];  // [k][o] 12 KB
    __shared__ float wT2[96 * 32];  // 12 KB
    int bid = blockIdx.x;
    int vh = bid & 1, l = (bid >> 1) & 63, n = bid >> 7;
    int t = threadIdx.x;
    int vl = t & 63, q = t >> 6;
    for (int i = t; i < 3072; i += 256) {
        int o = i / 96, k = i % 96;
        wT1[k * 32 + o] = w1[i];
        wT2[k * 32 + o] = w2[i];
    }
    __syncthreads();
    float acc[8][4];
#pragma unroll
    for (int oo = 0; oo < 8; oo++) {
        float bb = b1[q * 8 + oo] + b2[q * 8 + oo];
        acc[oo][0] = bb;
        acc[oo][1] = bb;
        acc[oo][2] = bb;
        acc[oo][3] = bb;
    }
    int uoff = vh * 128 + vl * 2;

#define LOADX(arr, ptr)                                        \
    {                                                          \
        uint2 hh = *(const uint2*)&(ptr)[jrow + uoff];         \
        uint2 ll = *(const uint2*)&(ptr)[jrow + 256 + uoff];   \
        arr[0] = ulo(hh.x) + ulo(ll.x);                        \
        arr[1] = uhi(hh.x) + uhi(ll.x);                        \
        arr[2] = ulo(hh.y) + ulo(ll.y);                        \
        arr[3] = uhi(hh.y) + uhi(ll.y);                        \
    }
#define FMA4(oidx, a0c, a1c, a2c, c0c, c1c, c2c)                              \
    {                                                                         \
        float wc0 = (a0c) + (c0c);                                            \
        acc[oidx][0] += x0[0] * wc0 + xa[0] * (a1c) + xb[0] * (a2c) +         \
                        xc[0] * (c1c) + xd[0] * (c2c);                        \
        acc[oidx][1] += x0[1] * wc0 + xa[1] * (a1c) + xb[1] * (a2c) +         \
                        xc[1] * (c1c) + xd[1] * (c2c);                        \
        acc[oidx][2] += x0[2] * wc0 + xa[2] * (a1c) + xb[2] * (a2c) +         \
                        xc[2] * (c1c) + xd[2] * (c2c);                        \
        acc[oidx][3] += x0[3] * wc0 + xa[3] * (a1c) + xb[3] * (a2c) +         \
                        xc[3] * (c1c) + xd[3] * (c2c);                        \
    }

    for (int c = 0; c < 32; c++) {
        int jrow = ((n * 32 + c) * 64 + l) * 512;
        float x0[4], xa[4], xb[4], xc[4], xd[4];
        LOADX(x0, h0);
        LOADX(xa, p1a);
        LOADX(xb, p2a);
        LOADX(xc, p1b);
        LOADX(xd, p2b);
#pragma unroll
        for (int ov = 0; ov < 2; ov++) {
            int wo = q * 8 + ov * 4;
            float4 wa0 = *(const float4*)&wT1[c * 32 + wo];
            float4 wa1 = *(const float4*)&wT1[(32 + c) * 32 + wo];
            float4 wa2 = *(const float4*)&wT1[(64 + c) * 32 + wo];
            float4 wb0 = *(const float4*)&wT2[c * 32 + wo];
            float4 wb1 = *(const float4*)&wT2[(32 + c) * 32 + wo];
            float4 wb2 = *(const float4*)&wT2[(64 + c) * 32 + wo];
            FMA4(ov * 4 + 0, wa0.x, wa1.x, wa2.x, wb0.x, wb1.x, wb2.x);
            FMA4(ov * 4 + 1, wa0.y, wa1.y, wa2.y, wb0.y, wb1.y, wb2.y);
            FMA4(ov * 4 + 2, wa0.z, wa1.z, wa2.z, wb0.z, wb1.z, wb2.z);
            FMA4(ov * 4 + 3, wa0.w, wa1.w, wa2.w, wb0.w, wb1.w, wb2.w);
        }
    }
#undef LOADX
#undef FMA4
#pragma unroll
    for (int oo = 0; oo < 8; oo++) {
        int o = q * 8 + oo;
        int jrow = ((n * 32 + o) * 64 + l) * 512;
        float a0 = acc[oo][0], a1 = acc[oo][1], a2 = acc[oo][2],
              a3 = acc[oo][3];
        unsigned short h0v = f2b(a0), h1v = f2b(a1), h2v = f2b(a2),
                       h3v = f2b(a3);
        uint2 hi, lo;
        hi.x = (unsigned int)h0v | ((unsigned int)h1v << 16);
        hi.y = (unsigned int)h2v | ((unsigned int)h3v << 16);
        lo.x = pk2(a0 - b2f(h0v), a1 - b2f(h1v));
        lo.y = pk2(a2 - b2f(h2v), a3 - b2f(h3v));
        *(uint2*)&dst_u[jrow + uoff] = hi;
        *(uint2*)&dst_u[jrow + 256 + uoff] = lo;
    }
}

// LayerNorm#1 + transpose to v-major: ht[(n*512+v)][c*64+l] packed u32.
__global__ __launch_bounds__(256) void lnt_kernel(
    const unsigned short* __restrict__ h, const float* __restrict__ lw,
    const float* __restrict__ lb, unsigned int* __restrict__ ht) {
    __shared__ float th[64][65];
    __shared__ unsigned int tt[64][65];
    __shared__ float p1s[4][64], p2s[4][64], ms[64], is[64];
    int b = blockIdx.x;
    int c = b & 31, vb = (b >> 5) & 7, n = b >> 8;
    int t = threadIdx.x;
#pragma unroll
    for (int half = 0; half < 2; half++) {
        int s = half * 256 + t;
        int l = s >> 3, q = s & 7;
        const unsigned short* p =
            h + (size_t)((n * 32 + c) * 64 + l) * 1024 + vb * 64 + q * 8;
        short8 hiv = *(const short8*)p;
        short8 lov = *(const short8*)(p + 512);
#pragma unroll
        for (int i = 0; i < 8; i++)
            th[l][q * 8 + i] =
                b2f((unsigned short)hiv[i]) + b2f((unsigned short)lov[i]);
    }
    __syncthreads();
    {
        int v = t & 63, g = t >> 6;
        float s = 0.f, sq = 0.f;
#pragma unroll
        for (int i = 0; i < 16; i++) {
            float f = th[g * 16 + i][v];
            s += f;
            sq += f * f;
        }
        p1s[g][v] = s;
        p2s[g][v] = sq;
    }
    __syncthreads();
    if (t < 64) {
        float s = p1s[0][t] + p1s[1][t] + p1s[2][t] + p1s[3][t];
        float sq = p2s[0][t] + p2s[1][t] + p2s[2][t] + p2s[3][t];
        float m = s * (1.f / 64.f);
        float var = fmaxf(sq * (1.f / 64.f) - m * m, 0.f);
        ms[t] = m;
        is[t] = 1.f / sqrtf(var + 1e-12f);
    }
    __syncthreads();
    {
        int v = t & 63, g = t >> 6;
        float m = ms[v], inv = is[v];
#pragma unroll
        for (int i = 0; i < 16; i++) {
            int l = g * 16 + i;
            float f = lw[l] * (th[l][v] - m) * inv + lb[l];
            unsigned short hi = f2b(f);
            tt[v][l] = (unsigned int)hi | ((unsigned int)f2b(f - b2f(hi)) << 16);
        }
    }
    __syncthreads();
    {
        int vr = t >> 2, ch = t & 3;
        unsigned int* dstp =
            ht + (size_t)(n * 512 + vb * 64 + vr) * 2048 + c * 64 + ch * 16;
#pragma unroll
        for (int i = 0; i < 4; i++) {
            uint4 val;
            val.x = tt[vr][ch * 16 + i * 4 + 0];
            val.y = tt[vr][ch * 16 + i * 4 + 1];
            val.z = tt[vr][ch * 16 + i * 4 + 2];
            val.w = tt[vr][ch * 16 + i * 4 + 3];
            *(uint4*)(dstp + i * 4) = val;
        }
    }
}

// fused end1+selu+end2+LN#2+sum. One wave per (n,v); 512 blocks x 256 thr.
// e1 bf16-packed in 32 u32 regs (round-9 exact, passing at 0.309).
__global__ __launch_bounds__(256, 2) void end_fused3(
    const unsigned int* __restrict__ ht, const float* __restrict__ w1,
    const float* __restrict__ b1, const float* __restrict__ w2,
    const float* __restrict__ b2, const float* __restrict__ lw,
    const float* __restrict__ lb, float* __restrict__ out) {
    __shared__ float w1s[64 * 32];
    __shared__ float w2s[64 * 64];
    __shared__ float b1s[64], b2s[64], lws[64], lbs[64];
    int t = threadIdx.x;
    for (int i = t; i < 2048; i += 256) w1s[i] = w1[i];
    for (int i = t; i < 4096; i += 256) w2s[i] = w2[i];
    if (t < 64) {
        b1s[t] = b1[t];
        b2s[t] = b2[t];
        lws[t] = lw[t];
        lbs[t] = lb[t];
    }
    __syncthreads();
    int wid = t >> 6, lane = t & 63;
    int gw = blockIdx.x * 4 + wid;
    int n = gw >> 9, v = gw & 511;
    const unsigned int* row = ht + (size_t)(n * 512 + v) * 2048;
    float hvf[32];
#pragma unroll
    for (int c = 0; c < 32; c++) {
        unsigned int u = row[c * 64 + lane];
        hvf[c] = ulo(u) + uhi(u);
    }
    unsigned int e1p[32];
#pragma unroll
    for (int op = 0; op < 32; op++) {
        float a0 = b1s[2 * op], a1 = b1s[2 * op + 1];
#pragma unroll
        for (int cq = 0; cq < 8; cq++) {
            float4 wa = *(const float4*)&w1s[(2 * op) * 32 + cq * 4];
            float4 wb = *(const float4*)&w1s[(2 * op + 1) * 32 + cq * 4];
            a0 += wa.x * hvf[cq * 4] + wa.y * hvf[cq * 4 + 1] +
                  wa.z * hvf[cq * 4 + 2] + wa.w * hvf[cq * 4 + 3];
            a1 += wb.x * hvf[cq * 4] + wb.y * hvf[cq * 4 + 1] +
                  wb.z * hvf[cq * 4 + 2] + wb.w * hvf[cq * 4 + 3];
        }
        e1p[op] = pk2(selu_f(a0), selu_f(a1));
    }
    float lwl = lws[lane], lbl = lbs[lane];
    float accout = 0.f;
    for (int o2 = 0; o2 < 64; o2++) {
        float pa = 0.f, pb = 0.f;
#pragma unroll
        for (int oq = 0; oq < 16; oq++) {
            float4 wv = *(const float4*)&w2s[o2 * 64 + oq * 4];
            unsigned int u0 = e1p[oq * 2];
            unsigned int u1 = e1p[oq * 2 + 1];
            pa += wv.x * ulo(u0) + wv.z * ulo(u1);
            pb += wv.y * uhi(u0) + wv.w * uhi(u1);
        }
        float e2 = b2s[o2] + (pa + pb);
        float sA = e2, sB = e2 * e2;
#pragma unroll
        for (int m = 1; m < 64; m <<= 1) {
            sA += __shfl_xor(sA, m, 64);
            sB += __shfl_xor(sB, m, 64);
        }
        float mean = sA * (1.f / 64.f);
        float var = fmaxf(sB * (1.f / 64.f) - mean * mean, 0.f);
        float inv = 1.f / sqrtf(var + 1e-12f);
        accout += lwl * (e2 - mean) * inv + lbl;
    }
    out[(n * 64 + lane) * 512 + v] = accout;
}

// ---------------- launch ----------------

extern "C" void kernel_launch(void* const* d_in, const int* in_sizes, int n_in,
                              void* d_out, int out_size, void* d_ws,
                              size_t ws_size, hipStream_t stream) {
    const float* x = (const float*)d_in[0];
    const float* emb1 = (const float*)d_in[1];
    const float* emb2 = (const float*)d_in[2];
    const float* lin1_w = (const float*)d_in[3];
    const float* lin1_b = (const float*)d_in[4];
    const float* lin2_w = (const float*)d_in[5];
    const float* lin2_b = (const float*)d_in[6];
    const float* start_w = (const float*)d_in[7];
    const float* start_b = (const float*)d_in[8];
    const float* g1_w = (const float*)d_in[9];
    const float* g1_b = (const float*)d_in[10];
    const float* g2_w = (const float*)d_in[11];
    const float* g2_b = (const float*)d_in[12];
    const float* ln_w = (const float*)d_in[13];
    const float* ln_b = (const float*)d_in[14];
    const float* end1_w = (const float*)d_in[15];
    const float* end1_b = (const float*)d_in[16];
    const float* end2_w = (const float*)d_in[17];
    const float* end2_b = (const float*)d_in[18];
    float* out = (float*)d_out;

    char* ws = (char*)d_ws;
    float* nv1 = (float*)(ws + 0);
    float* nv2 = (float*)(ws + 131072);
    float* adp = (float*)(ws + 262144);
    unsigned short* a1T = (unsigned short*)(ws + 1310720);
    unsigned short* a2T = (unsigned short*)(ws + 2359296);
    float* rowsump = (float*)(ws + 3407872);
    float* colsum = (float*)(ws + 3409920);
    float* cspart = (float*)(ws + 3412992);
    unsigned short* hA = (unsigned short*)(ws + 4194304);
    unsigned short* hB = (unsigned short*)(ws + 20971520);
    unsigned short* s1 = (unsigned short*)(ws + 37748736);
    unsigned short* s2 = (unsigned short*)(ws + 54525952);
    unsigned short* s3 = (unsigned short*)(ws + 71303168);
    unsigned short* s4 = (unsigned short*)(ws + 88080384);

    nodevec_kernel<<<512, 64, 0, stream>>>(emb1, lin1_w, lin1_b, nv1);
    nodevec_kernel<<<512, 64, 0, stream>>>(emb2, lin2_w, lin2_b, nv2);
    adjacency_kernel<<<512, 512, 0, stream>>>(nv1, nv2, adp);
    topk_kernel<<<512, 256, 0, stream>>>(adp, rowsump);
    colsum_part<<<16, 256, 0, stream>>>(adp, cspart);
    colsum_red<<<1, 512, 0, stream>>>(cspart, colsum);
    normalize_kernel<<<512, 256, 0, stream>>>(adp, rowsump, colsum, a1T, a2T);

    start_kernel<<<256, 256, 0, stream>>>(x, start_w, start_b, (unsigned int*)hA);

    dim3 pgrid(64, 8);
    unsigned short* cur = hA;
    unsigned short* nxt = hB;
    for (int layer = 0; layer < 2; layer++) {
        const float* w1 = g1_w + layer * 32 * 96;
        const float* bb1 = g1_b + layer * 32;
        const float* w2 = g2_w + layer * 32 * 96;
        const float* bb2 = g2_b + layer * 32;
        prop_pair<true><<<pgrid, 256, 0, stream>>>(cur, cur, cur, a1T, a2T,
                                                   s1, s2);
        prop_pair<false><<<pgrid, 256, 0, stream>>>(s1, s2, cur, a1T, a2T,
                                                    s3, s4);
        chanmix_v2<<<512, 256, 0, stream>>>(
            (const unsigned int*)cur, (const unsigned int*)s1,
            (const unsigned int*)s3, (const unsigned int*)s2,
            (const unsigned int*)s4, w1, bb1, w2, bb2, (unsigned int*)nxt);
        unsigned short* tmp = cur;
        cur = nxt;
        nxt = tmp;
    }

    lnt_kernel<<<1024, 256, 0, stream>>>(cur, ln_w, ln_b, (unsigned int*)s1);
    end_fused3<<<512, 256, 0, stream>>>((const unsigned int*)s1, end1_w,
                                        end1_b, end2_w, end2_b, ln_w, ln_b,
                                        out);
}